// Round 12
// baseline (137.693 us; speedup 1.0000x reference)
//
#include <hip/hip_runtime.h>
#include <hip/hip_bf16.h>
#include <math.h>

#define L_SEQ 1024
#define BSZ 8
#define EMB 512
#define NH 8
#define DQ 64
#define BH 64          // BSZ*NH
#define NQKV 1536      // 3*NH*DQ

// Q is pre-scaled by (emb_dim/n_head)^-0.5 * log2(e) so that
// softmax numerator = exp2(mfma_score) with zero extra VALU per element.
#define SCALE_Q 0.18033688f

typedef __attribute__((ext_vector_type(8))) short short8;   // 8 bf16 = 4 VGPR
typedef __attribute__((ext_vector_type(4))) float f32x4;

#define GPTR(x) ((const __attribute__((address_space(1))) void*)(x))
#define LPTR(x) ((__attribute__((address_space(3))) void*)(x))

__device__ __forceinline__ unsigned short bf16u(float x) {
  __hip_bfloat16 h = __float2bfloat16(x);
  return *(unsigned short*)&h;
}

// ---------------------------------------------------------------------------
// Kernel 0: f32 -> bf16 convert of emb (8192x512) and W (1536x512).
// Block 0 additionally zero-inits Oacc/cnt for attn_fused (kernel-boundary
// ordering guarantees visibility before any attn_fused atomicAdd).
// ---------------------------------------------------------------------------
__global__ __launch_bounds__(256) void to_bf16(
    const float* __restrict__ emb, const float* __restrict__ W,
    unsigned short* __restrict__ embB, unsigned short* __restrict__ WB,
    float* __restrict__ Oacc, int* __restrict__ cnt) {
  if (blockIdx.x == 0) {
    for (int i = threadIdx.x; i < BH * 64; i += 256) Oacc[i] = 0.f;
    if (threadIdx.x < BH) cnt[threadIdx.x] = 0;
  }
  const size_t t = (size_t)blockIdx.x * 256 + threadIdx.x;
  size_t base = t * 8;
  const float* src;
  unsigned short* dst;
  size_t off;
  if (base < (size_t)8192 * 512) { src = emb; dst = embB; off = base; }
  else { src = W; dst = WB; off = base - (size_t)8192 * 512; }
  float4 v0 = *(const float4*)&src[off];
  float4 v1 = *(const float4*)&src[off + 4];
  short8 o;
  o[0] = bf16u(v0.x); o[1] = bf16u(v0.y); o[2] = bf16u(v0.z); o[3] = bf16u(v0.w);
  o[4] = bf16u(v1.x); o[5] = bf16u(v1.y); o[6] = bf16u(v1.z); o[7] = bf16u(v1.w);
  *(short8*)&dst[off] = o;
}

// ---------------------------------------------------------------------------
// Kernel A: QKV projection, bf16 MFMA (m97 pattern). Q gets SCALE_Q folded in.
// Epilogue: C-tile staged to LDS (Cs[128][132] bf16), then each 64-col
// half-tile is a contiguous [bh][l][0..63] run -> short8 coalesced stores.
// ---------------------------------------------------------------------------
__global__ __launch_bounds__(256) void qkv_mfma(
    const unsigned short* __restrict__ A,   // embB [8192][512]
    const unsigned short* __restrict__ B,   // WB   [1536][512]
    const float* __restrict__ bias,
    unsigned short* __restrict__ Qb, unsigned short* __restrict__ Kb,
    unsigned short* __restrict__ Vb) {
  __shared__ __align__(16) unsigned short As[128][32];  // 8 KB, unpadded
  __shared__ __align__(16) unsigned short Bs[128][32];  // 8 KB
  __shared__ __align__(16) unsigned short Cs[128][132]; // 33 KB, +4 pad
  const int tid = threadIdx.x;
  const int wave = tid >> 6, lane = tid & 63;
  const int quad = lane >> 4, col = lane & 15;
  const int wr = wave >> 1, wc = wave & 1;
  const int m0 = blockIdx.y * 128, n0 = blockIdx.x * 128;
  const int r16 = lane >> 2, q4 = lane & 3;

  f32x4 acc[4][4] = {};

  for (int kt = 0; kt < EMB; kt += 32) {
    __syncthreads();
#pragma unroll
    for (int c = 0; c < 2; ++c) {
      const int rowA = (c * 4 + wave) * 16;
      __builtin_amdgcn_global_load_lds(
          GPTR(A + (size_t)(m0 + rowA + r16) * EMB + kt + q4 * 8),
          LPTR(&As[rowA][0]), 16, 0, 0);
      __builtin_amdgcn_global_load_lds(
          GPTR(B + (size_t)(n0 + rowA + r16) * EMB + kt + q4 * 8),
          LPTR(&Bs[rowA][0]), 16, 0, 0);
    }
    __syncthreads();
    short8 af[4], bf[4];
#pragma unroll
    for (int i = 0; i < 4; ++i)
      af[i] = *(const short8*)&As[wr * 64 + i * 16 + col][quad * 8];
#pragma unroll
    for (int j = 0; j < 4; ++j)
      bf[j] = *(const short8*)&Bs[wc * 64 + j * 16 + col][quad * 8];
#pragma unroll
    for (int i = 0; i < 4; ++i)
#pragma unroll
      for (int j = 0; j < 4; ++j)
        acc[i][j] =
            __builtin_amdgcn_mfma_f32_16x16x32_bf16(af[i], bf[j], acc[i][j],
                                                    0, 0, 0);
  }

#pragma unroll
  for (int j = 0; j < 4; ++j) {
    const int n = wc * 64 + j * 16 + col;     // tile col 0..127
    const float bj = bias[n0 + n];
    const bool isQ = (((n0 + n) >> 6) % 3) == 0;
#pragma unroll
    for (int i = 0; i < 4; ++i) {
      const int mrow = wr * 64 + i * 16 + quad * 4;
#pragma unroll
      for (int r = 0; r < 4; ++r) {
        float val = acc[i][j][r] + bj;
        if (isQ) val *= SCALE_Q;
        Cs[mrow + r][n] = bf16u(val);
      }
    }
  }
  __syncthreads();
  const int bb = lane >> 3, oct = lane & 7;
#pragma unroll
  for (int e = 0; e < 8; ++e) {
    const int idx = wave * 8 + e;
    const int half = idx >> 4, l = idx & 15;
    const int G = (n0 >> 6) + half;       // 64-col block id, 0..23
    const int h = G / 3, sel = G % 3;
    unsigned short* dst = (sel == 0) ? Qb : (sel == 1) ? Kb : Vb;
    short8 v = *(const short8*)&Cs[l * 8 + bb][half * 64 + oct * 8];
    const int lglob = (m0 >> 3) + l;
    *(short8*)&dst[(((size_t)(bb * NH + h)) * L_SEQ + lglob) * DQ + oct * 8] = v;
  }
}

// ---------------------------------------------------------------------------
// Kernel B (fully fused attention): one dispatch does z-pass, aw-pass,
// V-combine, and GroupNorm.
// 512 thr, grid 512 = (bh = blk&63 -> XCD-local, qc = blk>>6 in 0..7).
// Block owns 128 q-rows; wave owns 16 (A-operand fragments in registers).
// PASS 1: sweep all 16 K-tiles (dbuf LDS, post-barrier prefetch), zacc per
//   row -> butterfly -> invz[4] IN REGISTERS (no global invz round-trip).
// PASS 2: re-sweep the SAME K stream (L2-hot, same block), accumulate
//   cs[wave][m] = own-rows' contribution to key m's attn-weight.
// Reduce cs across waves; V-combine (O linear in aw => per-block partial
//   O = sum_m cs[m]*V[m][d] over ALL keys, broadcast cs reads, coalesced V);
// atomicAdd into Oacc[bh]; 8th block (cnt) does GroupNorm + out.
// Dbuf safety: pass-1 kt=15 reads buf1; pass-2 kt=0 writes buf0 whose last
// readers (pass-1 kt=14) are behind barrier(kt=15). In-loop pattern as R11.
// ---------------------------------------------------------------------------
__global__ __launch_bounds__(512) void attn_fused(
    const unsigned short* __restrict__ Qb, const unsigned short* __restrict__ Kb,
    const unsigned short* __restrict__ Vb,
    const float* __restrict__ gnw, const float* __restrict__ gnb,
    float* __restrict__ Oacc, int* __restrict__ cnt, float* __restrict__ out) {
  const int bh = blockIdx.x & 63;   // blk%8 = bh%8 -> same-bh blocks same XCD
  const int qc = blockIdx.x >> 6;   // 0..7, 128 q-rows each
  const int tid = threadIdx.x;
  const int wave = tid >> 6, lane = tid & 63;
  const int quad = lane >> 4, col = lane & 15;

  __shared__ __align__(16) unsigned short Ks[2][64][72];  // 18 KB
  __shared__ float cs[8][1024];                           // 32 KB
  __shared__ int lastFlag;

  const unsigned short* kbase = &Kb[(size_t)bh * L_SEQ * DQ];

  // Q fragments for this wave's 16 rows (used in both passes)
  const unsigned short* qp =
      &Qb[((size_t)bh * L_SEQ + qc * 128 + wave * 16 + col) * DQ];
  short8 qa0 = *(const short8*)&qp[quad * 8];
  short8 qa1 = *(const short8*)&qp[32 + quad * 8];

  const int sr = tid >> 3;        // staging row 0..63
  const int so = (tid & 7) * 8;   // staging col offset (shorts), 16B

  // ---------------- PASS 1: Z for own 128 rows ----------------
  float zacc[4] = {0.f, 0.f, 0.f, 0.f};
  short8 st0 = *(const short8*)(kbase + (size_t)sr * DQ + so);

#pragma unroll 2
  for (int kt = 0; kt < 16; ++kt) {
    const int buf = kt & 1;
    *(short8*)&Ks[buf][sr][so] = st0;
    __syncthreads();
    if (kt + 1 < 16) {  // post-barrier prefetch: in flight through compute
      st0 = *(const short8*)(kbase + ((size_t)((kt + 1) * 64 + sr)) * DQ + so);
    }
#pragma unroll
    for (int sub = 0; sub < 4; ++sub) {
      const unsigned short* kp = &Ks[buf][sub * 16 + col][0];
      short8 kb0 = *(const short8*)&kp[quad * 8];
      short8 kb1 = *(const short8*)&kp[32 + quad * 8];
      f32x4 s = {0.f, 0.f, 0.f, 0.f};
      s = __builtin_amdgcn_mfma_f32_16x16x32_bf16(qa0, kb0, s, 0, 0, 0);
      s = __builtin_amdgcn_mfma_f32_16x16x32_bf16(qa1, kb1, s, 0, 0, 0);
#pragma unroll
      for (int j = 0; j < 4; ++j) zacc[j] += __builtin_amdgcn_exp2f(s[j]);
    }
  }
  float invz[4];
#pragma unroll
  for (int j = 0; j < 4; ++j) {
    float z = zacc[j];
#pragma unroll
    for (int off = 1; off <= 8; off <<= 1) z += __shfl_xor(z, off, 64);
    invz[j] = __builtin_amdgcn_rcpf(z);   // replicated across the quad
  }

  // ---------------- PASS 2: colsum contributions (K is L2-hot) ----------
  st0 = *(const short8*)(kbase + (size_t)sr * DQ + so);
#pragma unroll 2
  for (int kt = 0; kt < 16; ++kt) {
    const int buf = kt & 1;
    *(short8*)&Ks[buf][sr][so] = st0;
    __syncthreads();
    if (kt + 1 < 16) {
      st0 = *(const short8*)(kbase + ((size_t)((kt + 1) * 64 + sr)) * DQ + so);
    }
#pragma unroll
    for (int sub = 0; sub < 4; ++sub) {
      const unsigned short* kp = &Ks[buf][sub * 16 + col][0];
      short8 kb0 = *(const short8*)&kp[quad * 8];
      short8 kb1 = *(const short8*)&kp[32 + quad * 8];
      f32x4 s = {0.f, 0.f, 0.f, 0.f};
      s = __builtin_amdgcn_mfma_f32_16x16x32_bf16(qa0, kb0, s, 0, 0, 0);
      s = __builtin_amdgcn_mfma_f32_16x16x32_bf16(qa1, kb1, s, 0, 0, 0);
      float partial = 0.f;
#pragma unroll
      for (int j = 0; j < 4; ++j)
        partial = fmaf(__builtin_amdgcn_exp2f(s[j]), invz[j], partial);
      // sum over the 4 quads (this wave's 16 rows); key = kt*64+sub*16+col
      partial += __shfl_xor(partial, 16, 64);
      partial += __shfl_xor(partial, 32, 64);
      if (quad == 0) cs[wave][kt * 64 + sub * 16 + col] = partial;
    }
  }
  __syncthreads();
  // reduce cs over the 8 waves -> cs[0][m]
  for (int m = tid; m < 1024; m += 512) {
    float a = cs[0][m] + cs[1][m] + cs[2][m] + cs[3][m] +
              cs[4][m] + cs[5][m] + cs[6][m] + cs[7][m];
    cs[0][m] = a;
  }
  __syncthreads();

  // V-combine: partial O[d] = sum over ALL 1024 keys of cs[0][m]*V[m][d]
  const int d = tid & 63, g8 = tid >> 6;   // 8 groups x 128 keys
  {
    const unsigned short* vb = &Vb[((size_t)bh * L_SEQ + g8 * 128) * DQ + d];
    float oacc = 0.f;
#pragma unroll 8
    for (int mm = 0; mm < 128; ++mm) {
      __hip_bfloat16 v;
      *(unsigned short*)&v = vb[(size_t)mm * DQ];
      oacc = fmaf(cs[0][g8 * 128 + mm], __bfloat162float(v), oacc);
    }
    cs[1][g8 * 64 + d] = oacc;   // cs[1] rows free after reduce
  }
  __syncthreads();
  if (tid < 64) {
    float p = 0.f;
#pragma unroll
    for (int g = 0; g < 8; ++g) p += cs[1][g * 64 + tid];
    atomicAdd(&Oacc[(size_t)bh * 64 + tid], p);
  }
  if (tid == 0) {
    __threadfence();                      // release: O adds visible first
    lastFlag = (atomicAdd(&cnt[bh], 1) == 7);
  }
  __syncthreads();
  if (lastFlag && tid < 64) {
    __threadfence();                      // acquire
    float v = atomicAdd(&Oacc[(size_t)bh * 64 + tid], 0.f);
    float s = v;
#pragma unroll
    for (int off = 32; off >= 1; off >>= 1) s += __shfl_xor(s, off, 64);
    float mean = s * (1.f / 64.f);
    float diff = v - mean;
    float sq = diff * diff;
#pragma unroll
    for (int off = 32; off >= 1; off >>= 1) sq += __shfl_xor(sq, off, 64);
    float var = sq * (1.f / 64.f);
    float o = diff * rsqrtf(var + 1e-5f);
    const int b = bh >> 3, h = bh & 7;
    out[(size_t)b * 512 + h * 64 + tid] = o * gnw[h] + gnb[h];
  }
}

extern "C" void kernel_launch(void* const* d_in, const int* in_sizes, int n_in,
                              void* d_out, int out_size, void* d_ws,
                              size_t ws_size, hipStream_t stream) {
  (void)in_sizes; (void)n_in; (void)out_size; (void)ws_size;
  const float* emb  = (const float*)d_in[0];
  const float* W    = (const float*)d_in[1];
  const float* bias = (const float*)d_in[2];
  const float* gnw  = (const float*)d_in[3];
  const float* gnb  = (const float*)d_in[4];
  float* out = (float*)d_out;

  char* ws = (char*)d_ws;
  const size_t perQ = (size_t)BH * L_SEQ * DQ;        // 4,194,304 elems
  unsigned short* embB = (unsigned short*)ws;                      // 8 MB
  unsigned short* WB   = (unsigned short*)(ws + 8u * 1024 * 1024); // 1.5 MB
  unsigned short* Qb   = (unsigned short*)(ws + 10u * 1024 * 1024);
  unsigned short* Kb   = Qb + perQ;   // @18M
  unsigned short* Vb   = Kb + perQ;   // @26M
  float* Oacc = (float*)(ws + 35u * 1024 * 1024);     // 16 KB
  int*   cnt  = (int*)(ws + 35u * 1024 * 1024 + 64u * 1024);

  to_bf16<<<dim3(2432), 256, 0, stream>>>(emb, W, embB, WB, Oacc, cnt);
  qkv_mfma<<<dim3(NQKV / 128, 8192 / 128), 256, 0, stream>>>(
      embB, WB, bias, Qb, Kb, Vb);
  attn_fused<<<dim3(512), 512, 0, stream>>>(Qb, Kb, Vb, gnw, gnb,
                                            Oacc, cnt, out);
}